// Round 1
// baseline (1376.196 us; speedup 1.0000x reference)
//
#include <hip/hip_runtime.h>
#include <math.h>

#define BATCH 8192
#define NB 8          // batch elements per wave-lane-set (wave handles NB batch cols)
#define NCOL 512
#define MNODE 256

// ---------------------------------------------------------------------------
// Pre-compute per-node constants into d_ws:
// pp[3n+0] = (cos phi, sin phi, cos theta, sin theta)
// pp[3n+1] = (A_L, C1_L, C2_L, S_L)   left DC:  vt' = A*vt + i*C1*vb ; vb' = i*C2*vt + S*vb
// pp[3n+2] = (A_R, C1_R, C2_R, S_R)   right DC
// where A = ins*sin(pi/4+e), C1 = cos(pi/4+e), C2 = ins*cos(pi/4+e), S = sin(pi/4+e)
// ---------------------------------------------------------------------------
__global__ __launch_bounds__(256) void precomp_kernel(
    const float* __restrict__ thetas, const float* __restrict__ phis,
    const float* __restrict__ bse, const float* __restrict__ lse,
    float4* __restrict__ pp) {
  int n = blockIdx.x * 256 + threadIdx.x;
  float th = thetas[n], ph = phis[n];
  float e0 = bse[2 * n + 0], e1 = bse[2 * n + 1];
  float l0 = lse[2 * n + 0], l1 = lse[2 * n + 1];
  const float K = 0.16609640474436813f;  // log2(10)/20  (10^(L/20) = 2^(K*L))
  float ins0 = exp2f(l0 * K), ins1 = exp2f(l1 * K);
  const float PI4 = 0.7853981633974483f;
  float s0, c0, s1, c1, sp, cp, st, ct;
  sincosf(PI4 + e0, &s0, &c0);
  sincosf(PI4 + e1, &s1, &c1);
  sincosf(ph, &sp, &cp);
  sincosf(th, &st, &ct);
  pp[3 * n + 0] = make_float4(cp, sp, ct, st);
  pp[3 * n + 1] = make_float4(ins0 * s0, c0, ins0 * c0, s0);
  pp[3 * n + 2] = make_float4(ins1 * s1, c1, ins1 * c1, s1);
}

// One full node: phase(phi) on top; left DC; phase(theta) on top; right DC.
// 24 FMA-class ops. DC exploits: s11,s22 real; s12,s21 pure imaginary.
__device__ __forceinline__ void proc_pair(float& vtr, float& vti, float& vbr, float& vbi,
                                          const float4 ph, const float4 L, const float4 R) {
  // vt *= exp(i*phi)
  float tr = ph.x * vtr - ph.y * vti;
  float ti = ph.x * vti + ph.y * vtr;
  // left DC: vt' = A*vt + i*C1*vb ; vb' = i*C2*vt + S*vb
  float atr = L.x * tr - L.y * vbi;
  float ati = L.x * ti + L.y * vbr;
  float abr = L.w * vbr - L.z * ti;
  float abi = L.w * vbi + L.z * tr;
  // vt *= exp(i*theta)
  tr = ph.z * atr - ph.w * ati;
  ti = ph.z * ati + ph.w * atr;
  // right DC
  vtr = R.x * tr - R.y * abi;
  vti = R.x * ti + R.y * abr;
  vbr = R.w * abr - R.z * ti;
  vbi = R.w * abi + R.z * tr;
}

// ---------------------------------------------------------------------------
// Main mesh sweep. Lane l of each wave owns rows 8l..8l+7 for NB batch cols.
// State lives in registers (128 VGPRs). Even columns: 4 in-lane pairs.
// Odd columns: 3 in-lane pairs + 1 cross-lane pair via shuffles.
// Row 0 untouched in odd cols (lane0 guarded); node j=255 of odd cols is
// masked == lane 63's cross pair (write suppressed).
// ---------------------------------------------------------------------------
__global__ __launch_bounds__(256, 1) void mesh_kernel(
    const float* __restrict__ x, const float* __restrict__ gammas,
    const float4* __restrict__ pp, float* __restrict__ out) {
  const int lane = threadIdx.x & 63;
  const int wid = (blockIdx.x * blockDim.x + threadIdx.x) >> 6;
  const int b0 = wid * NB;

  float vr[8][NB], vi[8][NB];

  // init: v = x * exp(i*gamma)
#pragma unroll
  for (int r = 0; r < 8; ++r) {
    const int row = lane * 8 + r;
    float sg, cg;
    sincosf(gammas[row], &sg, &cg);
    const float4* xp = (const float4*)(x + (size_t)row * BATCH + b0);
    float4 x0 = xp[0], x1 = xp[1];
    float xb[NB] = {x0.x, x0.y, x0.z, x0.w, x1.x, x1.y, x1.z, x1.w};
#pragma unroll
    for (int q = 0; q < NB; ++q) {
      vr[r][q] = xb[q] * cg;
      vi[r][q] = xb[q] * sg;
    }
  }

  float4 pe[12], po[12];
  {
    const float4* p0 = pp + (size_t)(4 * lane) * 3;
#pragma unroll
    for (int i = 0; i < 12; ++i) pe[i] = p0[i];
  }

#pragma unroll 1
  for (int c = 0; c < NCOL; c += 2) {
    // prefetch odd column c+1 params (nodes (c+1)*256 + 4l .. +3)
    {
      const float4* pO = pp + ((size_t)(c + 1) * MNODE + 4 * lane) * 3;
#pragma unroll
      for (int i = 0; i < 12; ++i) po[i] = pO[i];
    }

    // ---- even column c: pairs (2k, 2k+1) in-lane, node j = 4*lane + k
#pragma unroll
    for (int k = 0; k < 4; ++k) {
#pragma unroll
      for (int q = 0; q < NB; ++q)
        proc_pair(vr[2 * k][q], vi[2 * k][q], vr[2 * k + 1][q], vi[2 * k + 1][q],
                  pe[3 * k], pe[3 * k + 1], pe[3 * k + 2]);
    }

    // prefetch even column c+2 params (clamped; last iter value unused)
    {
      const int c2 = (c + 2 < NCOL) ? (c + 2) : 0;
      const float4* pE = pp + ((size_t)c2 * MNODE + 4 * lane) * 3;
#pragma unroll
      for (int i = 0; i < 12; ++i) pe[i] = pE[i];
    }

    // ---- odd column c+1: in-lane pairs (2k+1, 2k+2), node j = 4*lane + k
#pragma unroll
    for (int k = 0; k < 3; ++k) {
#pragma unroll
      for (int q = 0; q < NB; ++q)
        proc_pair(vr[2 * k + 1][q], vi[2 * k + 1][q], vr[2 * k + 2][q], vi[2 * k + 2][q],
                  po[3 * k], po[3 * k + 1], po[3 * k + 2]);
    }
    // cross-lane pair: (row 8l+7 here, row 8(l+1) in lane l+1), node j = 4*lane+3
#pragma unroll
    for (int q = 0; q < NB; ++q) {
      float br = __shfl_down(vr[0][q], 1, 64);  // neighbor's row0 (pre-update this col)
      float bi = __shfl_down(vi[0][q], 1, 64);
      float tr = vr[7][q], ti = vi[7][q];
      proc_pair(tr, ti, br, bi, po[9], po[10], po[11]);
      float nbr = __shfl_up(br, 1, 64);  // send updated bottom back to lane l+1
      float nbi = __shfl_up(bi, 1, 64);
      if (lane < 63) { vr[7][q] = tr; vi[7][q] = ti; }  // lane63 = masked node j=255
      if (lane > 0)  { vr[0][q] = nbr; vi[0][q] = nbi; }  // lane0 row0 untouched
    }
  }

  // store: out[0] = real, out[1] = imag, each (512, 8192)
#pragma unroll
  for (int r = 0; r < 8; ++r) {
    const int row = lane * 8 + r;
    float4 o0 = make_float4(vr[r][0], vr[r][1], vr[r][2], vr[r][3]);
    float4 o1 = make_float4(vr[r][4], vr[r][5], vr[r][6], vr[r][7]);
    float4 i0 = make_float4(vi[r][0], vi[r][1], vi[r][2], vi[r][3]);
    float4 i1 = make_float4(vi[r][4], vi[r][5], vi[r][6], vi[r][7]);
    float4* orp = (float4*)(out + (size_t)row * BATCH + b0);
    float4* oip = (float4*)(out + (size_t)(512 * BATCH) + (size_t)row * BATCH + b0);
    orp[0] = o0; orp[1] = o1;
    oip[0] = i0; oip[1] = i1;
  }
}

extern "C" void kernel_launch(void* const* d_in, const int* in_sizes, int n_in,
                              void* d_out, int out_size, void* d_ws, size_t ws_size,
                              hipStream_t stream) {
  const float* x      = (const float*)d_in[0];
  const float* thetas = (const float*)d_in[1];
  const float* phis   = (const float*)d_in[2];
  const float* gammas = (const float*)d_in[3];
  const float* bse    = (const float*)d_in[4];
  const float* lse    = (const float*)d_in[5];
  // top/bottom/mask (d_in[6..8]) are deterministic (Clements mesh) — derived analytically.

  float4* pp = (float4*)d_ws;  // 131072 nodes * 3 float4 = 6 MB

  precomp_kernel<<<512, 256, 0, stream>>>(thetas, phis, bse, lse, pp);

  // 8192 batch / NB=8 per wave = 1024 waves = 256 blocks of 4 waves
  mesh_kernel<<<256, 256, 0, stream>>>(x, gammas, pp, (float*)d_out);
}

// Round 2
// 989.776 us; speedup vs baseline: 1.3904x; 1.3904x over previous
//
#include <hip/hip_runtime.h>
#include <math.h>

#define BATCH 8192
#define NB 4          // batch elements per lane; 8192/4 = 2048 waves = 2 waves/SIMD
#define NCOL 512
#define MNODE 256

// ---------------------------------------------------------------------------
// Pre-compute the FUSED per-node 2x2 complex matrix:
//   N = R * diag(e^{i*theta},1) * L * diag(e^{i*phi},1)
// where L = [[A_L, i*C1_L],[i*C2_L, S_L]],  A = ins*sin(pi/4+e), C1 = cos(pi/4+e),
// C2 = ins*cos(pi/4+e), S = sin(pi/4+e)  (matches reference _dc_terms/_transform:
// top' = t11*vt + t21*vb ; bot' = t12*vt + t22*vb).
// Layout: pp[2n+0] = (n11r, n11i, n12r, n12i); pp[2n+1] = (n21r, n21i, n22r, n22i)
// ---------------------------------------------------------------------------
__global__ __launch_bounds__(256) void precomp_kernel(
    const float* __restrict__ thetas, const float* __restrict__ phis,
    const float* __restrict__ bse, const float* __restrict__ lse,
    float4* __restrict__ pp) {
  int n = blockIdx.x * 256 + threadIdx.x;
  float th = thetas[n], ph = phis[n];
  float e0 = bse[2 * n + 0], e1 = bse[2 * n + 1];
  float l0 = lse[2 * n + 0], l1 = lse[2 * n + 1];
  const float K = 0.16609640474436813f;  // log2(10)/20
  float ins0 = exp2f(l0 * K), ins1 = exp2f(l1 * K);
  const float PI4 = 0.7853981633974483f;
  float s0, c0, s1, c1, sp, cp, st, ct;
  sincosf(PI4 + e0, &s0, &c0);
  sincosf(PI4 + e1, &s1, &c1);
  sincosf(ph, &sp, &cp);
  sincosf(th, &st, &ct);
  float AL = ins0 * s0, C1L = c0, C2L = ins0 * c0, SL = s0;
  float AR = ins1 * s1, C1R = c1, C2R = ins1 * c1, SR = s1;
  // a = L * diag(e^{i phi}, 1)
  float a11r = AL * cp,   a11i = AL * sp;
  float a12r = 0.f,       a12i = C1L;
  float a21r = -C2L * sp, a21i = C2L * cp;
  float a22r = SL,        a22i = 0.f;
  // b = diag(e^{i theta}, 1) * a  (top row only)
  float b11r = a11r * ct - a11i * st, b11i = a11r * st + a11i * ct;
  float b12r = a12r * ct - a12i * st, b12i = a12r * st + a12i * ct;
  // N = R * b ;  R = [[AR, i*C1R],[i*C2R, SR]]
  float n11r = AR * b11r - C1R * a21i;
  float n11i = AR * b11i + C1R * a21r;
  float n12r = AR * b12r - C1R * a22i;
  float n12i = AR * b12i + C1R * a22r;
  float n21r = -C2R * b11i + SR * a21r;
  float n21i =  C2R * b11r + SR * a21i;
  float n22r = -C2R * b12i + SR * a22r;
  float n22i =  C2R * b12r + SR * a22i;
  pp[2 * n + 0] = make_float4(n11r, n11i, n12r, n12i);
  pp[2 * n + 1] = make_float4(n21r, n21i, n22r, n22i);
}

// General complex 2x2 apply: 16 FMA-class ops.
__device__ __forceinline__ void proc_pair(float& vtr, float& vti, float& vbr, float& vbi,
                                          const float4 q0, const float4 q1) {
  float tr = q0.x * vtr - q0.y * vti + q0.z * vbr - q0.w * vbi;
  float ti = q0.x * vti + q0.y * vtr + q0.z * vbi + q0.w * vbr;
  float br = q1.x * vtr - q1.y * vti + q1.z * vbr - q1.w * vbi;
  float bi = q1.x * vti + q1.y * vtr + q1.z * vbi + q1.w * vbr;
  vtr = tr; vti = ti; vbr = br; vbi = bi;
}

// ---------------------------------------------------------------------------
// Mesh sweep. Lane l owns rows 8l..8l+7 for NB batch cols; state in registers
// (64 VGPRs). Even cols: 4 in-lane pairs (node j=4l+k, rows 8l+2k,8l+2k+1).
// Odd cols: 3 in-lane pairs (j=4l+k, rows 8l+2k+1,8l+2k+2) + 1 cross-lane pair
// (j=4l+3, rows 8l+7 and 8(l+1)) via shuffles. Lane63's cross pair is exactly
// the masked node j=255 (writes suppressed); lane0's row 0 untouched in odd
// cols — matches the reference mesh exactly (validated round 1).
// ---------------------------------------------------------------------------
__global__ __launch_bounds__(256, 2) void mesh_kernel(
    const float* __restrict__ x, const float* __restrict__ gammas,
    const float4* __restrict__ pp, float* __restrict__ out) {
  const int lane = threadIdx.x & 63;
  const int wid = (blockIdx.x * blockDim.x + threadIdx.x) >> 6;
  const int b0 = wid * NB;

  float vr[8][NB], vi[8][NB];

  // init: v = x * exp(i*gamma)
#pragma unroll
  for (int r = 0; r < 8; ++r) {
    const int row = lane * 8 + r;
    float sg, cg;
    sincosf(gammas[row], &sg, &cg);
    float4 x0 = *(const float4*)(x + (size_t)row * BATCH + b0);
    float xb[NB] = {x0.x, x0.y, x0.z, x0.w};
#pragma unroll
    for (int q = 0; q < NB; ++q) {
      vr[r][q] = xb[q] * cg;
      vi[r][q] = xb[q] * sg;
    }
  }

  float4 pe[8], po[8];
  {
    const float4* p0 = pp + (size_t)(4 * lane) * 2;
#pragma unroll
    for (int i = 0; i < 8; ++i) pe[i] = p0[i];
  }

#pragma unroll 1
  for (int c = 0; c < NCOL; c += 2) {
    // prefetch odd column c+1 params (nodes (c+1)*256 + 4l .. +3)
    {
      const float4* pO = pp + ((size_t)(c + 1) * MNODE + 4 * lane) * 2;
#pragma unroll
      for (int i = 0; i < 8; ++i) po[i] = pO[i];
    }

    // ---- even column c
#pragma unroll
    for (int k = 0; k < 4; ++k) {
#pragma unroll
      for (int q = 0; q < NB; ++q)
        proc_pair(vr[2 * k][q], vi[2 * k][q], vr[2 * k + 1][q], vi[2 * k + 1][q],
                  pe[2 * k], pe[2 * k + 1]);
    }

    // prefetch even column c+2 params (clamped; last-iter value unused)
    {
      const int c2 = (c + 2 < NCOL) ? (c + 2) : 0;
      const float4* pE = pp + ((size_t)c2 * MNODE + 4 * lane) * 2;
#pragma unroll
      for (int i = 0; i < 8; ++i) pe[i] = pE[i];
    }

    // ---- odd column c+1: in-lane pairs
#pragma unroll
    for (int k = 0; k < 3; ++k) {
#pragma unroll
      for (int q = 0; q < NB; ++q)
        proc_pair(vr[2 * k + 1][q], vi[2 * k + 1][q], vr[2 * k + 2][q], vi[2 * k + 2][q],
                  po[2 * k], po[2 * k + 1]);
    }
    // cross-lane pair: (row 8l+7 here, row 8(l+1) in lane l+1), node j = 4l+3
#pragma unroll
    for (int q = 0; q < NB; ++q) {
      float br = __shfl_down(vr[0][q], 1, 64);  // neighbor's row0 (pre-update)
      float bi = __shfl_down(vi[0][q], 1, 64);
      float tr = vr[7][q], ti = vi[7][q];
      proc_pair(tr, ti, br, bi, po[6], po[7]);
      float nbr = __shfl_up(br, 1, 64);  // return updated bottom to owner
      float nbi = __shfl_up(bi, 1, 64);
      if (lane < 63) { vr[7][q] = tr; vi[7][q] = ti; }   // lane63 = masked j=255
      if (lane > 0)  { vr[0][q] = nbr; vi[0][q] = nbi; } // lane0 row0 untouched
    }
  }

  // store: out[0]=real, out[1]=imag, each (512, 8192)
#pragma unroll
  for (int r = 0; r < 8; ++r) {
    const int row = lane * 8 + r;
    *(float4*)(out + (size_t)row * BATCH + b0) =
        make_float4(vr[r][0], vr[r][1], vr[r][2], vr[r][3]);
    *(float4*)(out + (size_t)(512 * BATCH) + (size_t)row * BATCH + b0) =
        make_float4(vi[r][0], vi[r][1], vi[r][2], vi[r][3]);
  }
}

extern "C" void kernel_launch(void* const* d_in, const int* in_sizes, int n_in,
                              void* d_out, int out_size, void* d_ws, size_t ws_size,
                              hipStream_t stream) {
  const float* x      = (const float*)d_in[0];
  const float* thetas = (const float*)d_in[1];
  const float* phis   = (const float*)d_in[2];
  const float* gammas = (const float*)d_in[3];
  const float* bse    = (const float*)d_in[4];
  const float* lse    = (const float*)d_in[5];
  // top/bottom/mask (d_in[6..8]) are deterministic (Clements mesh) — derived analytically.

  float4* pp = (float4*)d_ws;  // 131072 nodes * 2 float4 = 4 MB

  precomp_kernel<<<512, 256, 0, stream>>>(thetas, phis, bse, lse, pp);

  // 8192 / NB=4 = 2048 waves = 512 blocks of 4 waves; 2 blocks/CU = 2 waves/SIMD
  mesh_kernel<<<512, 256, 0, stream>>>(x, gammas, pp, (float*)d_out);
}